// Round 14
// baseline (785.380 us; speedup 1.0000x reference)
//
#include <hip/hip_runtime.h>
#include <stdint.h>

#define NPTS 8192
#define NPAIR 4096
#define NB 4
#define KNN 16
#define RQ 2          // queries (rows) per wave; one point-pair = both queries
#define CAP 1024      // per-query u16 survivor buffer
#define TRIG 512      // tighten when cnt >= TRIG (checked per fat iter; +512 max -> <= 1023)
#define NSLOT 16      // CAP / 64

typedef unsigned long long u64;
typedef unsigned int u32;
typedef unsigned short u16;

__device__ __forceinline__ u32 f2ord(float f) {
    u32 b = __float_as_uint(f);
    return (b & 0x80000000u) ? ~b : (b | 0x80000000u);
}
__device__ __forceinline__ float ord2f(u32 u) {
    u32 b = (u & 0x80000000u) ? (u & 0x7fffffffu) : ~u;
    return __uint_as_float(b);
}
__device__ __forceinline__ u64 shflx64(u64 v, int m) {
    u32 lo = (u32)v, hi = (u32)(v >> 32);
    lo = __shfl_xor(lo, m, 64);
    hi = __shfl_xor(hi, m, 64);
    return ((u64)hi << 32) | lo;
}

// Pair-packed SoA: pos8[(b*NPAIR+m)*2+0] = {x0,x1,y0,y1}, +1 = {z0,z1,sq0,sq1}.
// sq via mul-add chain (np.sum(p*p)): ((x*x + y*y) + z*z), all _rn.
__global__ __launch_bounds__(256) void pack_kernel(const float* __restrict__ pos,
                                                   float4* __restrict__ pos8) {
    int t = blockIdx.x * 256 + threadIdx.x;   // 0..16383
    int b = t >> 12;
    int m = t & (NPAIR - 1);
    const float* p = pos + (size_t)b * 3 * NPTS;
    float2 x = *(const float2*)&p[2 * m];
    float2 y = *(const float2*)&p[NPTS + 2 * m];
    float2 z = *(const float2*)&p[2 * NPTS + 2 * m];
    float s0 = __fadd_rn(__fadd_rn(__fmul_rn(x.x, x.x), __fmul_rn(y.x, y.x)), __fmul_rn(z.x, z.x));
    float s1 = __fadd_rn(__fadd_rn(__fmul_rn(x.y, x.y), __fmul_rn(y.y, y.y)), __fmul_rn(z.y, z.y));
    pos8[2 * t]     = make_float4(x.x, x.y, y.x, y.y);
    pos8[2 * t + 1] = make_float4(z.x, z.y, s0, s1);
}

// reference-exact distance for candidate pair (a,c) against query r
#define DIST(r, a, c, d0, d1)                                                           \
    { float dot0 = __fmaf_rn(qz[r], (c).x, __fmaf_rn(qy[r], (a).z, __fmul_rn(qx[r], (a).x))); \
      float dot1 = __fmaf_rn(qz[r], (c).y, __fmaf_rn(qy[r], (a).w, __fmul_rn(qx[r], (a).y))); \
      d0 = __fsub_rn(__fadd_rn(qw[r], (c).z), __fmul_rn(2.0f, dot0));                   \
      d1 = __fsub_rn(__fadd_rn(qw[r], (c).w), __fmul_rn(2.0f, dot1)); }

// recompute d2 for stored candidate index (bit-identical ops)
#define RECOMP(r, idx, d2out)                                                           \
    { int _m = (int)(idx) >> 1, _h = (int)(idx) & 1;                                    \
      float4 _a = P8[2 * _m], _c = P8[2 * _m + 1];                                      \
      float _px = _h ? _a.y : _a.x, _py = _h ? _a.w : _a.z;                             \
      float _pz = _h ? _c.y : _c.x, _pw = _h ? _c.w : _c.z;                             \
      float _dot = __fmaf_rn(qz[r], _pz, __fmaf_rn(qy[r], _py, __fmul_rn(qx[r], _px))); \
      d2out = __fsub_rn(__fadd_rn(qw[r], _pw), __fmul_rn(2.0f, _dot)); }

// One wave serves RQ=2 consecutive rows. Fat-body scan: 8 independent float4
// loads per iteration (MLP), 16 distances batched into registers, then one
// ballot pass per query. Survivors go to per-query u16 index buffers; d2 is
// recomputed when needed. Exactness: after every tighten, >=16 buffer entries
// have key <= T-key; all buffered entries precede future candidates in index,
// so ties lose -> pruning d2 >= T is exact.
__global__ __launch_bounds__(256, 4) void knn_kernel(const float4* __restrict__ pos8,
                                                     float* __restrict__ out) {
    __shared__ u16 buf[4][RQ][CAP];
    const int lane = threadIdx.x & 63;
    const int wv = threadIdx.x >> 6;
    const int rowbase = blockIdx.x * 8 + wv * RQ;   // 8 rows per block (even)
    const int b = rowbase >> 13;
    const int ib = rowbase & (NPTS - 1);
    const float4* __restrict__ P8 = pos8 + (size_t)b * NPAIR * 2;
    const u64 below = (1ull << lane) - 1ull;

    // query registers: both rows come from one pair (ib even)
    float qx[RQ], qy[RQ], qz[RQ], qw[RQ];
    {
        int m = ib >> 1;
        float4 a = P8[2 * m], c = P8[2 * m + 1];
        qx[0] = a.x; qy[0] = a.z; qz[0] = c.x; qw[0] = c.z;
        qx[1] = a.y; qy[1] = a.w; qz[1] = c.y; qw[1] = c.w;
    }

    float T[RQ];
    int cnt[RQ];

    // 16th-smallest of the 64 per-lane values (u32), via bitonic sort + bcast
    auto rank16 = [&](u32 v) -> u32 {
#pragma unroll
        for (int k = 2; k <= 64; k <<= 1)
#pragma unroll
            for (int j = k >> 1; j >= 1; j >>= 1) {
                u32 o = __shfl_xor(v, j, 64);
                bool up = ((lane & k) == 0) == ((lane & j) == 0);
                v = (up ? (v < o) : (v > o)) ? v : o;
            }
        return (u32)__shfl((int)v, 15, 64);
    };

    // tighten query r: T' = 16th-smallest per-lane-min, compact to <= T'.
    // Fallback (adversarial): exact 16-round extract-min -> winners in buf.
    auto tighten = [&](int r) {
        u32 ordv[NSLOT], idxv[NSLOT];
        u32 mn = 0xFFFFFFFFu;
#pragma unroll
        for (int t = 0; t < NSLOT; ++t) {
            int bi = t * 64 + lane;
            bool val = bi < cnt[r];
            u32 idx = val ? (u32)buf[wv][r][bi] : 0u;
            float d2;
            RECOMP(r, idx, d2);
            u32 o = val ? f2ord(d2) : 0xFFFFFFFFu;
            ordv[t] = o; idxv[t] = idx;
            mn = o < mn ? o : mn;
        }
        u32 hi = rank16(mn);
        int rc = 0;
#pragma unroll
        for (int t = 0; t < NSLOT; ++t) rc += (int)__popcll(__ballot(ordv[t] <= hi));
        if (rc <= 256) {
            int nc = 0;
#pragma unroll
            for (int t = 0; t < NSLOT; ++t) {
                bool keep = ordv[t] <= hi;
                u64 bal = __ballot(keep);
                if (keep) buf[wv][r][nc + (int)__popcll(bal & below)] = (u16)idxv[t];
                nc += (int)__popcll(bal);
            }
            cnt[r] = nc;
            T[r] = ord2f(hi);
        } else {
            u64 s16[NSLOT];
#pragma unroll
            for (int t = 0; t < NSLOT; ++t) s16[t] = ((u64)ordv[t] << 13) | idxv[t];
            u64 mm = 0;
#pragma unroll 1
            for (int rr = 0; rr < KNN; ++rr) {
                u64 lm = s16[0];
#pragma unroll
                for (int t = 1; t < NSLOT; ++t) lm = s16[t] < lm ? s16[t] : lm;
                mm = lm;
#pragma unroll
                for (int s = 1; s < 64; s <<= 1) { u64 o = shflx64(mm, s); mm = o < mm ? o : mm; }
#pragma unroll
                for (int t = 0; t < NSLOT; ++t) s16[t] = (s16[t] == mm) ? ~0ULL : s16[t];
                if (lane == 0) buf[wv][r][rr] = (u16)(mm & (u64)(NPTS - 1));
            }
            cnt[r] = KNN;
            T[r] = ord2f((u32)(mm >> 13));
        }
    };

    // ---- bootstrap: candidates 0..511 (pairs 0..255) in registers ----
    {
        float d2v[RQ][8];
#pragma unroll
        for (int s = 0; s < 4; ++s) {
            int m = s * 64 + lane;
            float4 a = P8[2 * m], c = P8[2 * m + 1];
#pragma unroll
            for (int r = 0; r < RQ; ++r) DIST(r, a, c, d2v[r][2 * s], d2v[r][2 * s + 1]);
        }
#pragma unroll
        for (int r = 0; r < RQ; ++r) {
            u32 mn = 0xFFFFFFFFu;
#pragma unroll
            for (int t = 0; t < 8; ++t) { u32 o = f2ord(d2v[r][t]); mn = o < mn ? o : mn; }
            u32 hi = rank16(mn);
            int nc = 0;
#pragma unroll
            for (int t = 0; t < 8; ++t) {
                bool keep = f2ord(d2v[r][t]) <= hi;
                u64 bal = __ballot(keep);
                if (keep)
                    buf[wv][r][nc + (int)__popcll(bal & below)] =
                        (u16)(2 * ((t >> 1) * 64 + lane) + (t & 1));
                nc += (int)__popcll(bal);
            }
            cnt[r] = nc;
            T[r] = ord2f(hi);
        }
    }

    // ---- steady scan: 15 fat iterations of 256 pairs (512 cands/query) ----
#pragma unroll 1
    for (int g = 1; g < 16; ++g) {
        if (cnt[0] >= TRIG) tighten(0);   // wave-uniform; invariant cnt <= 511 here
        if (cnt[1] >= TRIG) tighten(1);
        int gbase = g * 256;
        float4 a[4], c[4];
#pragma unroll
        for (int s = 0; s < 4; ++s) {
            int m = gbase + s * 64 + lane;
            a[s] = P8[2 * m];
            c[s] = P8[2 * m + 1];
        }
        float d2[RQ][8];
#pragma unroll
        for (int s = 0; s < 4; ++s)
#pragma unroll
            for (int r = 0; r < RQ; ++r) DIST(r, a[s], c[s], d2[r][2 * s], d2[r][2 * s + 1]);
#pragma unroll
        for (int r = 0; r < RQ; ++r) {
            bool pp[8];
            u64 bb[8];
            u64 any = 0;
#pragma unroll
            for (int t = 0; t < 8; ++t) {
                pp[t] = d2[r][t] < T[r];
                bb[t] = __ballot(pp[t]);
                any |= bb[t];
            }
            if (any) {
                int base = cnt[r];
#pragma unroll
                for (int t = 0; t < 8; ++t) {
                    if (pp[t])
                        buf[wv][r][base + (int)__popcll(bb[t] & below)] =
                            (u16)(2 * (gbase + (t >> 1) * 64 + lane) + (t & 1));
                    base += (int)__popcll(bb[t]);
                }
                cnt[r] = base;
            }
        }
    }

    // ---- final per query: compact if large, then bitonic sort-64 on keys ----
#pragma unroll
    for (int r = 0; r < RQ; ++r) {
        if (cnt[r] > 64) tighten(r);          // typical result: ~16-30 entries
        u64 myk = ~0ULL;
        if (cnt[r] <= 64) {
            bool val = lane < cnt[r];
            u32 idx = val ? (u32)buf[wv][r][lane] : 0u;
            float d2;
            RECOMP(r, idx, d2);
            u64 v = val ? (((u64)f2ord(d2) << 13) | idx) : ~0ULL;
#pragma unroll
            for (int k = 2; k <= 64; k <<= 1)
#pragma unroll
                for (int j = k >> 1; j >= 1; j >>= 1) {
                    u64 o = shflx64(v, j);
                    bool up = ((lane & k) == 0) == ((lane & j) == 0);
                    v = (up ? (v < o) : (v > o)) ? v : o;
                }
            myk = v;   // lane holds rank = lane
        } else {
            // adversarial path: exact extract-min tournament (cnt <= 256 here)
            u64 s16[NSLOT];
#pragma unroll
            for (int t = 0; t < NSLOT; ++t) {
                int bi = t * 64 + lane;
                bool val = bi < cnt[r];
                u32 idx = val ? (u32)buf[wv][r][bi] : 0u;
                float d2;
                RECOMP(r, idx, d2);
                s16[t] = val ? (((u64)f2ord(d2) << 13) | idx) : ~0ULL;
            }
#pragma unroll 1
            for (int rr = 0; rr < KNN; ++rr) {
                u64 lm = s16[0];
#pragma unroll
                for (int t = 1; t < NSLOT; ++t) lm = s16[t] < lm ? s16[t] : lm;
                u64 mm = lm;
#pragma unroll
                for (int s = 1; s < 64; s <<= 1) { u64 o = shflx64(mm, s); mm = o < mm ? o : mm; }
#pragma unroll
                for (int t = 0; t < NSLOT; ++t) s16[t] = (s16[t] == mm) ? ~0ULL : s16[t];
                if (lane == rr) myk = mm;
            }
        }
        if (lane < KNN) {
            int iq = ib + r;
            size_t o1 = (size_t)(b * KNN + lane) * NPTS + iq;
            out[o1] = (float)(u32)(myk & (u64)(NPTS - 1));
            out[(size_t)NB * KNN * NPTS + o1] = ord2f((u32)(myk >> 13));
        }
    }
}

extern "C" void kernel_launch(void* const* d_in, const int* in_sizes, int n_in,
                              void* d_out, int out_size, void* d_ws, size_t ws_size,
                              hipStream_t stream) {
    const float* pos = (const float*)d_in[0];
    float* out = (float*)d_out;
    float4* pos8 = (float4*)d_ws;   // 4*4096*2*16 B = 512 KB scratch

    pack_kernel<<<dim3(NB * NPAIR / 256), dim3(256), 0, stream>>>(pos, pos8);
    knn_kernel<<<dim3(NB * NPTS / 8), dim3(256), 0, stream>>>(pos8, out);
}

// Round 15
// 286.029 us; speedup vs baseline: 2.7458x; 2.7458x over previous
//
#include <hip/hip_runtime.h>
#include <stdint.h>

#define NPTS 8192
#define NPAIR 4096
#define NB 4
#define KNN 16
#define RQ 2          // queries (rows) per wave; one point-pair = both queries
#define CAP 1024      // per-query u16 survivor buffer
#define TRIG 512      // tighten when cnt >= TRIG (checked per fat iter; +512 max -> <= 1023)
#define NSLOT 16      // CAP / 64

typedef unsigned long long u64;
typedef unsigned int u32;
typedef unsigned short u16;

__device__ __forceinline__ u32 f2ord(float f) {
    u32 b = __float_as_uint(f);
    return (b & 0x80000000u) ? ~b : (b | 0x80000000u);
}
__device__ __forceinline__ float ord2f(u32 u) {
    u32 b = (u & 0x80000000u) ? (u & 0x7fffffffu) : ~u;
    return __uint_as_float(b);
}
__device__ __forceinline__ u64 shflx64(u64 v, int m) {
    u32 lo = (u32)v, hi = (u32)(v >> 32);
    lo = __shfl_xor(lo, m, 64);
    hi = __shfl_xor(hi, m, 64);
    return ((u64)hi << 32) | lo;
}

// Pair-packed SoA: pos8[(b*NPAIR+m)*2+0] = {x0,x1,y0,y1}, +1 = {z0,z1,sq0,sq1}.
// sq via mul-add chain (np.sum(p*p)): ((x*x + y*y) + z*z), all _rn.
__global__ __launch_bounds__(256) void pack_kernel(const float* __restrict__ pos,
                                                   float4* __restrict__ pos8) {
    int t = blockIdx.x * 256 + threadIdx.x;   // 0..16383
    int b = t >> 12;
    int m = t & (NPAIR - 1);
    const float* p = pos + (size_t)b * 3 * NPTS;
    float2 x = *(const float2*)&p[2 * m];
    float2 y = *(const float2*)&p[NPTS + 2 * m];
    float2 z = *(const float2*)&p[2 * NPTS + 2 * m];
    float s0 = __fadd_rn(__fadd_rn(__fmul_rn(x.x, x.x), __fmul_rn(y.x, y.x)), __fmul_rn(z.x, z.x));
    float s1 = __fadd_rn(__fadd_rn(__fmul_rn(x.y, x.y), __fmul_rn(y.y, y.y)), __fmul_rn(z.y, z.y));
    pos8[2 * t]     = make_float4(x.x, x.y, y.x, y.y);
    pos8[2 * t + 1] = make_float4(z.x, z.y, s0, s1);
}

// reference-exact distance for candidate pair (a,c) against query r
#define DIST(r, a, c, d0, d1)                                                           \
    { float dot0 = __fmaf_rn(qz[r], (c).x, __fmaf_rn(qy[r], (a).z, __fmul_rn(qx[r], (a).x))); \
      float dot1 = __fmaf_rn(qz[r], (c).y, __fmaf_rn(qy[r], (a).w, __fmul_rn(qx[r], (a).y))); \
      d0 = __fsub_rn(__fadd_rn(qw[r], (c).z), __fmul_rn(2.0f, dot0));                   \
      d1 = __fsub_rn(__fadd_rn(qw[r], (c).w), __fmul_rn(2.0f, dot1)); }

// recompute d2 for stored candidate index (bit-identical ops)
#define RECOMP(r, idx, d2out)                                                           \
    { int _m = (int)(idx) >> 1, _h = (int)(idx) & 1;                                    \
      float4 _a = P8[2 * _m], _c = P8[2 * _m + 1];                                      \
      float _px = _h ? _a.y : _a.x, _py = _h ? _a.w : _a.z;                             \
      float _pz = _h ? _c.y : _c.x, _pw = _h ? _c.w : _c.z;                             \
      float _dot = __fmaf_rn(qz[r], _pz, __fmaf_rn(qy[r], _py, __fmul_rn(qx[r], _px))); \
      d2out = __fsub_rn(__fadd_rn(qw[r], _pw), __fmul_rn(2.0f, _dot)); }

// One wave serves RQ=2 consecutive rows. Fat-body scan: 8 independent float4
// loads per iteration (memory-level parallelism), 16 distances batched into
// registers, then per-slot ballot-append (no staging arrays -> no spill).
// Exactness: after every tighten, >=16 buffer entries have key <= T-key; all
// buffered entries precede future candidates in index, so ties lose ->
// pruning d2 >= T is exact.
__global__ __launch_bounds__(256) void knn_kernel(const float4* __restrict__ pos8,
                                                  float* __restrict__ out) {
    __shared__ u16 buf[4][RQ][CAP];
    const int lane = threadIdx.x & 63;
    const int wv = threadIdx.x >> 6;
    const int rowbase = blockIdx.x * 8 + wv * RQ;   // 8 rows per block (even)
    const int b = rowbase >> 13;
    const int ib = rowbase & (NPTS - 1);
    const float4* __restrict__ P8 = pos8 + (size_t)b * NPAIR * 2;
    const u64 below = (1ull << lane) - 1ull;

    // query registers: both rows come from one pair (ib even)
    float qx[RQ], qy[RQ], qz[RQ], qw[RQ];
    {
        int m = ib >> 1;
        float4 a = P8[2 * m], c = P8[2 * m + 1];
        qx[0] = a.x; qy[0] = a.z; qz[0] = c.x; qw[0] = c.z;
        qx[1] = a.y; qy[1] = a.w; qz[1] = c.y; qw[1] = c.w;
    }

    float T[RQ];
    int cnt[RQ];

    // 16th-smallest of the 64 per-lane values (u32), via bitonic sort + bcast
    auto rank16 = [&](u32 v) -> u32 {
#pragma unroll
        for (int k = 2; k <= 64; k <<= 1)
#pragma unroll
            for (int j = k >> 1; j >= 1; j >>= 1) {
                u32 o = __shfl_xor(v, j, 64);
                bool up = ((lane & k) == 0) == ((lane & j) == 0);
                v = (up ? (v < o) : (v > o)) ? v : o;
            }
        return (u32)__shfl((int)v, 15, 64);
    };

    // tighten query r: T' = 16th-smallest per-lane-min, compact to <= T'.
    // Fallback (adversarial): exact 16-round extract-min -> winners in buf.
    auto tighten = [&](int r) {
        u32 ordv[NSLOT], idxv[NSLOT];
        u32 mn = 0xFFFFFFFFu;
#pragma unroll
        for (int t = 0; t < NSLOT; ++t) {
            int bi = t * 64 + lane;
            bool val = bi < cnt[r];
            u32 idx = val ? (u32)buf[wv][r][bi] : 0u;
            float d2;
            RECOMP(r, idx, d2);
            u32 o = val ? f2ord(d2) : 0xFFFFFFFFu;
            ordv[t] = o; idxv[t] = idx;
            mn = o < mn ? o : mn;
        }
        u32 hi = rank16(mn);
        int rc = 0;
#pragma unroll
        for (int t = 0; t < NSLOT; ++t) rc += (int)__popcll(__ballot(ordv[t] <= hi));
        if (rc <= 256) {
            int nc = 0;
#pragma unroll
            for (int t = 0; t < NSLOT; ++t) {
                bool keep = ordv[t] <= hi;
                u64 bal = __ballot(keep);
                if (keep) buf[wv][r][nc + (int)__popcll(bal & below)] = (u16)idxv[t];
                nc += (int)__popcll(bal);
            }
            cnt[r] = nc;
            T[r] = ord2f(hi);
        } else {
            u64 s16[NSLOT];
#pragma unroll
            for (int t = 0; t < NSLOT; ++t) s16[t] = ((u64)ordv[t] << 13) | idxv[t];
            u64 mm = 0;
#pragma unroll 1
            for (int rr = 0; rr < KNN; ++rr) {
                u64 lm = s16[0];
#pragma unroll
                for (int t = 1; t < NSLOT; ++t) lm = s16[t] < lm ? s16[t] : lm;
                mm = lm;
#pragma unroll
                for (int s = 1; s < 64; s <<= 1) { u64 o = shflx64(mm, s); mm = o < mm ? o : mm; }
#pragma unroll
                for (int t = 0; t < NSLOT; ++t) s16[t] = (s16[t] == mm) ? ~0ULL : s16[t];
                if (lane == 0) buf[wv][r][rr] = (u16)(mm & (u64)(NPTS - 1));
            }
            cnt[r] = KNN;
            T[r] = ord2f((u32)(mm >> 13));
        }
    };

    // ---- bootstrap: candidates 0..511 (pairs 0..255) in registers ----
    {
        float d2v[RQ][8];
#pragma unroll
        for (int s = 0; s < 4; ++s) {
            int m = s * 64 + lane;
            float4 a = P8[2 * m], c = P8[2 * m + 1];
#pragma unroll
            for (int r = 0; r < RQ; ++r) DIST(r, a, c, d2v[r][2 * s], d2v[r][2 * s + 1]);
        }
#pragma unroll
        for (int r = 0; r < RQ; ++r) {
            u32 mn = 0xFFFFFFFFu;
#pragma unroll
            for (int t = 0; t < 8; ++t) { u32 o = f2ord(d2v[r][t]); mn = o < mn ? o : mn; }
            u32 hi = rank16(mn);
            int nc = 0;
#pragma unroll
            for (int t = 0; t < 8; ++t) {
                bool keep = f2ord(d2v[r][t]) <= hi;
                u64 bal = __ballot(keep);
                if (keep)
                    buf[wv][r][nc + (int)__popcll(bal & below)] =
                        (u16)(2 * ((t >> 1) * 64 + lane) + (t & 1));
                nc += (int)__popcll(bal);
            }
            cnt[r] = nc;
            T[r] = ord2f(hi);
        }
    }

    // ---- steady scan: 15 fat iterations of 256 pairs (512 cands/query) ----
#pragma unroll 1
    for (int g = 1; g < 16; ++g) {
        if (cnt[0] >= TRIG) tighten(0);   // wave-uniform; invariant cnt <= 511 here
        if (cnt[1] >= TRIG) tighten(1);
        int gbase = g * 256;
        float4 a[4], c[4];
#pragma unroll
        for (int s = 0; s < 4; ++s) {
            int m = gbase + s * 64 + lane;
            a[s] = P8[2 * m];
            c[s] = P8[2 * m + 1];
        }
        float d2[RQ][8];
#pragma unroll
        for (int s = 0; s < 4; ++s)
#pragma unroll
            for (int r = 0; r < RQ; ++r) DIST(r, a[s], c[s], d2[r][2 * s], d2[r][2 * s + 1]);
#pragma unroll
        for (int r = 0; r < RQ; ++r) {
            int base = cnt[r];
#pragma unroll
            for (int t = 0; t < 8; ++t) {
                bool p = d2[r][t] < T[r];
                u64 bal = __ballot(p);
                if (p)
                    buf[wv][r][base + (int)__popcll(bal & below)] =
                        (u16)(2 * (gbase + (t >> 1) * 64 + lane) + (t & 1));
                base += (int)__popcll(bal);
            }
            cnt[r] = base;
        }
    }

    // ---- final per query: compact if large, then bitonic sort-64 on keys ----
#pragma unroll
    for (int r = 0; r < RQ; ++r) {
        if (cnt[r] > 64) tighten(r);          // typical result: ~16-30 entries
        u64 myk = ~0ULL;
        if (cnt[r] <= 64) {
            bool val = lane < cnt[r];
            u32 idx = val ? (u32)buf[wv][r][lane] : 0u;
            float d2;
            RECOMP(r, idx, d2);
            u64 v = val ? (((u64)f2ord(d2) << 13) | idx) : ~0ULL;
#pragma unroll
            for (int k = 2; k <= 64; k <<= 1)
#pragma unroll
                for (int j = k >> 1; j >= 1; j >>= 1) {
                    u64 o = shflx64(v, j);
                    bool up = ((lane & k) == 0) == ((lane & j) == 0);
                    v = (up ? (v < o) : (v > o)) ? v : o;
                }
            myk = v;   // lane holds rank = lane
        } else {
            // adversarial path: exact extract-min tournament (cnt <= 256 here)
            u64 s16[NSLOT];
#pragma unroll
            for (int t = 0; t < NSLOT; ++t) {
                int bi = t * 64 + lane;
                bool val = bi < cnt[r];
                u32 idx = val ? (u32)buf[wv][r][bi] : 0u;
                float d2;
                RECOMP(r, idx, d2);
                s16[t] = val ? (((u64)f2ord(d2) << 13) | idx) : ~0ULL;
            }
#pragma unroll 1
            for (int rr = 0; rr < KNN; ++rr) {
                u64 lm = s16[0];
#pragma unroll
                for (int t = 1; t < NSLOT; ++t) lm = s16[t] < lm ? s16[t] : lm;
                u64 mm = lm;
#pragma unroll
                for (int s = 1; s < 64; s <<= 1) { u64 o = shflx64(mm, s); mm = o < mm ? o : mm; }
#pragma unroll
                for (int t = 0; t < NSLOT; ++t) s16[t] = (s16[t] == mm) ? ~0ULL : s16[t];
                if (lane == rr) myk = mm;
            }
        }
        if (lane < KNN) {
            int iq = ib + r;
            size_t o1 = (size_t)(b * KNN + lane) * NPTS + iq;
            out[o1] = (float)(u32)(myk & (u64)(NPTS - 1));
            out[(size_t)NB * KNN * NPTS + o1] = ord2f((u32)(myk >> 13));
        }
    }
}

extern "C" void kernel_launch(void* const* d_in, const int* in_sizes, int n_in,
                              void* d_out, int out_size, void* d_ws, size_t ws_size,
                              hipStream_t stream) {
    const float* pos = (const float*)d_in[0];
    float* out = (float*)d_out;
    float4* pos8 = (float4*)d_ws;   // 4*4096*2*16 B = 512 KB scratch

    pack_kernel<<<dim3(NB * NPAIR / 256), dim3(256), 0, stream>>>(pos, pos8);
    knn_kernel<<<dim3(NB * NPTS / 8), dim3(256), 0, stream>>>(pos8, out);
}

// Round 16
// 201.359 us; speedup vs baseline: 3.9004x; 1.4205x over previous
//
#include <hip/hip_runtime.h>
#include <stdint.h>

#define NPTS 8192
#define NPAIR 4096
#define NB 4
#define KNN 16
#define RQ 2          // queries (rows) per wave
#define CCAP 24       // per-lane private column capacity (u16 indices)
#define DCAP 256      // dense staging for final select (>= 16 lanes * 16 entries)
#define MARGIN 1.5e-3f  // conservative filter slack >> f32 rounding of |vals|<=~1600

typedef unsigned long long u64;
typedef unsigned int u32;
typedef unsigned short u16;
typedef float f32x2 __attribute__((ext_vector_type(2)));

__device__ __forceinline__ u32 f2ord(float f) {
    u32 b = __float_as_uint(f);
    return (b & 0x80000000u) ? ~b : (b | 0x80000000u);
}
__device__ __forceinline__ float ord2f(u32 u) {
    u32 b = (u & 0x80000000u) ? (u & 0x7fffffffu) : ~u;
    return __uint_as_float(b);
}
__device__ __forceinline__ u64 shflx64(u64 v, int m) {
    u32 lo = (u32)v, hi = (u32)(v >> 32);
    lo = __shfl_xor(lo, m, 64);
    hi = __shfl_xor(hi, m, 64);
    return ((u64)hi << 32) | lo;
}

// Pair-packed SoA: pos8[(b*NPAIR+m)*2+0] = {x0,x1,y0,y1}, +1 = {z0,z1,sq0,sq1}.
// sq via mul-add chain (np.sum(p*p)): ((x*x + y*y) + z*z), all _rn.
__global__ __launch_bounds__(256) void pack_kernel(const float* __restrict__ pos,
                                                   float4* __restrict__ pos8) {
    int t = blockIdx.x * 256 + threadIdx.x;   // 0..16383
    int b = t >> 12;
    int m = t & (NPAIR - 1);
    const float* p = pos + (size_t)b * 3 * NPTS;
    float2 x = *(const float2*)&p[2 * m];
    float2 y = *(const float2*)&p[NPTS + 2 * m];
    float2 z = *(const float2*)&p[2 * NPTS + 2 * m];
    float s0 = __fadd_rn(__fadd_rn(__fmul_rn(x.x, x.x), __fmul_rn(y.x, y.x)), __fmul_rn(z.x, z.x));
    float s1 = __fadd_rn(__fadd_rn(__fmul_rn(x.y, x.y), __fmul_rn(y.y, y.y)), __fmul_rn(z.y, z.y));
    pos8[2 * t]     = make_float4(x.x, x.y, y.x, y.y);
    pos8[2 * t + 1] = make_float4(z.x, z.y, s0, s1);
}

// exact reference d2 for stored candidate index (BLAS-fma dot, _rn combine)
#define RECOMP(r, idx, d2out)                                                           \
    { int _m = (int)(idx) >> 1, _h = (int)(idx) & 1;                                    \
      float4 _a = P8[2 * _m], _c = P8[2 * _m + 1];                                      \
      float _px = _h ? _a.y : _a.x, _py = _h ? _a.w : _a.z;                             \
      float _pz = _h ? _c.y : _c.x, _pw = _h ? _c.w : _c.z;                             \
      float _dot = __fmaf_rn(qz[r], _pz, __fmaf_rn(qy[r], _py, __fmul_rn(qx[r], _px))); \
      d2out = __fsub_rn(__fadd_rn(qw[r], _pw), __fmul_rn(2.0f, _dot)); }

// One wave serves RQ=2 rows. Scan filter uses packed-f32 (v_pk_fma) values as
// a CONSERVATIVE test (val = fma(-2,dot,pw) < (T - qw) + MARGIN admits every
// candidate with exact d2 < T; MARGIN >> rounding slack). Survivors go to
// per-lane private LDS columns (no ballots in the hot loop); exact _rn d2 is
// recomputed for survivors at tighten/final, so ranking is bit-exact.
// Tighten: T' = 16th-smallest of the 64 per-lane min-d2 (bitonic): >=16
// entries (16 distinct lanes) have d2 <= T'; all buffered entries precede
// future candidates in index, so pruned (d2 > T'+slack) candidates and
// discarded entries each have >=16 strictly-smaller (d2,idx) keys -> exact.
// Post-compact only the 16 witness lanes stay populated; per-lane trim keeps
// the 16 smallest keys of a lane (a dropped entry has >=16 smaller in-lane),
// bounding survivors <= 256 = DCAP.
__global__ __launch_bounds__(256) void knn_kernel(const float4* __restrict__ pos8,
                                                  float* __restrict__ out) {
    __shared__ u16 col[4][RQ][CCAP][64];
    __shared__ u16 dense[4][RQ][DCAP];
    const int lane = threadIdx.x & 63;
    const int wv = threadIdx.x >> 6;
    const int rowbase = blockIdx.x * (4 * RQ) + wv * RQ;   // 8 rows per block
    const int b = rowbase >> 13;
    const int ib = rowbase & (NPTS - 1);
    const float4* __restrict__ P8 = pos8 + (size_t)b * NPAIR * 2;
    const u64 below = (1ull << lane) - 1ull;

    float qx[RQ], qy[RQ], qz[RQ], qw[RQ];
    {
        int m = ib >> 1;   // ib even: both rows come from one pair
        float4 a = P8[2 * m], cc = P8[2 * m + 1];
        qx[0] = a.x; qy[0] = a.z; qz[0] = cc.x; qw[0] = cc.z;
        qx[1] = a.y; qy[1] = a.w; qz[1] = cc.y; qw[1] = cc.w;
    }
    f32x2 qxv[RQ], qyv[RQ], qzv[RQ];
#pragma unroll
    for (int r = 0; r < RQ; ++r) {
        qxv[r] = (f32x2){qx[r], qx[r]};
        qyv[r] = (f32x2){qy[r], qy[r]};
        qzv[r] = (f32x2){qz[r], qz[r]};
    }
    const f32x2 n2v = {-2.0f, -2.0f};

    float Tm[RQ];   // filter threshold (T - qw) + MARGIN
    int c[RQ];      // per-lane column count (VGPR, divergent)

    // tighten: exact recompute of own column, T' = 16th lane-min, lane-local
    // compact (+ rare per-lane trim to 16). Lane-local except one bitonic.
    auto tighten = [&](int r) {
        // pass 1: per-lane min ord (exact d2) over own entries
        u32 mn = 0xFFFFFFFFu;
#pragma unroll
        for (int t = 0; t < CCAP; ++t) {
            if (t < c[r]) {
                u32 idx = (u32)col[wv][r][t][lane];
                float d2; RECOMP(r, idx, d2);
                u32 o = f2ord(d2);
                mn = o < mn ? o : mn;
            }
        }
        // rank-16 of the 64 lane-mins via u32 bitonic sort-64
        u32 v = mn;
#pragma unroll
        for (int k = 2; k <= 64; k <<= 1)
#pragma unroll
            for (int j = k >> 1; j >= 1; j >>= 1) {
                u32 o = (u32)__shfl_xor((int)v, j, 64);
                bool up = ((lane & k) == 0) == ((lane & j) == 0);
                v = (up ? (v < o) : (v > o)) ? v : o;
            }
        u32 ordK = (u32)__shfl((int)v, 15, 64);
        // pass 2: lane-local compact to entries with ord <= ordK
        int nc = 0;
#pragma unroll
        for (int t = 0; t < CCAP; ++t) {
            if (t < c[r]) {
                u32 idx = (u32)col[wv][r][t][lane];
                float d2; RECOMP(r, idx, d2);
                if (f2ord(d2) <= ordK) { col[wv][r][nc][lane] = (u16)idx; ++nc; }
            }
        }
        c[r] = nc;
        // pass 3 (rare): trim lane to its 16 smallest keys (exact-safe)
#pragma unroll 1
        for (int it = 0; it < CCAP - 16; ++it) {
            if (c[r] > 16) {
                u64 mx = 0; int mt = 0;
#pragma unroll
                for (int t = 0; t < CCAP; ++t) {
                    if (t < c[r]) {
                        u32 idx = (u32)col[wv][r][t][lane];
                        float d2; RECOMP(r, idx, d2);
                        u64 key = ((u64)f2ord(d2) << 13) | idx;
                        if (key > mx) { mx = key; mt = t; }
                    }
                }
                col[wv][r][mt][lane] = col[wv][r][c[r] - 1][lane];
                c[r] -= 1;
            }
        }
        Tm[r] = (ord2f(ordK) - qw[r]) + MARGIN;
    };

    // ---- bootstrap: candidates 0..511 appended unconditionally (no math) ----
#pragma unroll
    for (int s = 0; s < 4; ++s) {
        int m = s * 64 + lane;
#pragma unroll
        for (int r = 0; r < RQ; ++r) {
            col[wv][r][2 * s][lane]     = (u16)(2 * m);
            col[wv][r][2 * s + 1][lane] = (u16)(2 * m + 1);
        }
    }
    c[0] = 8; c[1] = 8;
    tighten(0); tighten(1);

    // ---- steady scan: 15 iters x 4 pair-slots (512 candidates/query/iter) ----
#pragma unroll 1
    for (int g = 1; g < 16; ++g) {
        // trigger: post-tighten c <= 16, appends <= 8 -> never exceeds CCAP=24
        if (__ballot(c[0] >= CCAP - 8)) tighten(0);
        if (__ballot(c[1] >= CCAP - 8)) tighten(1);
        int base = g * 256;
        float4 A[4], C[4];
#pragma unroll
        for (int s = 0; s < 4; ++s) {
            int m = base + s * 64 + lane;
            A[s] = P8[2 * m];
            C[s] = P8[2 * m + 1];
        }
#pragma unroll
        for (int s = 0; s < 4; ++s) {
            int m = base + s * 64 + lane;
            f32x2 x01 = {A[s].x, A[s].y}, y01 = {A[s].z, A[s].w};
            f32x2 z01 = {C[s].x, C[s].y}, sq01 = {C[s].z, C[s].w};
#pragma unroll
            for (int r = 0; r < RQ; ++r) {
                f32x2 dot01 = __builtin_elementwise_fma(
                    qzv[r], z01, __builtin_elementwise_fma(qyv[r], y01, qxv[r] * x01));
                f32x2 val01 = __builtin_elementwise_fma(n2v, dot01, sq01);
                if (val01.x < Tm[r]) { col[wv][r][c[r]][lane] = (u16)(2 * m);     c[r]++; }
                if (val01.y < Tm[r]) { col[wv][r][c[r]][lane] = (u16)(2 * m + 1); c[r]++; }
            }
        }
    }

    // ---- final per query ----
#pragma unroll
    for (int r = 0; r < RQ; ++r) {
        int sum = c[r];
#pragma unroll
        for (int s2 = 1; s2 < 64; s2 <<= 1) sum += __shfl_xor(sum, s2, 64);
        if (sum > 64) tighten(r);   // bounds survivors to <= 256
        // gather own columns into dense staging (slot-walk ballot-append)
        int nc = 0;
#pragma unroll 1
        for (int t = 0; t < CCAP; ++t) {
            bool valid = t < c[r];
            u64 bal = __ballot(valid);
            if (!bal) break;
            if (valid) dense[wv][r][nc + (int)__popcll(bal & below)] = col[wv][r][t][lane];
            nc += (int)__popcll(bal);
        }
        u64 myk = ~0ULL;
        if (nc <= 64) {
            bool valid = lane < nc;
            u32 idx = valid ? (u32)dense[wv][r][lane] : 0u;
            float d2; RECOMP(r, idx, d2);
            u64 v = valid ? (((u64)f2ord(d2) << 13) | idx) : ~0ULL;
#pragma unroll
            for (int k = 2; k <= 64; k <<= 1)
#pragma unroll
                for (int j = k >> 1; j >= 1; j >>= 1) {
                    u64 o = shflx64(v, j);
                    bool up = ((lane & k) == 0) == ((lane & j) == 0);
                    v = (up ? (v < o) : (v > o)) ? v : o;
                }
            myk = v;   // lane holds rank = lane
        } else {
            // rare path: exact extract-min tournament over <= 256 keys
            u64 s4[4];
#pragma unroll
            for (int t = 0; t < 4; ++t) {
                int bi = t * 64 + lane;
                bool valid = bi < nc;
                u32 idx = valid ? (u32)dense[wv][r][bi] : 0u;
                float d2; RECOMP(r, idx, d2);
                s4[t] = valid ? (((u64)f2ord(d2) << 13) | idx) : ~0ULL;
            }
#pragma unroll 1
            for (int rr = 0; rr < KNN; ++rr) {
                u64 lm = s4[0];
#pragma unroll
                for (int t = 1; t < 4; ++t) lm = s4[t] < lm ? s4[t] : lm;
                u64 mm = lm;
#pragma unroll
                for (int s2 = 1; s2 < 64; s2 <<= 1) { u64 o = shflx64(mm, s2); mm = o < mm ? o : mm; }
#pragma unroll
                for (int t = 0; t < 4; ++t) s4[t] = (s4[t] == mm) ? ~0ULL : s4[t];
                if (lane == rr) myk = mm;
            }
        }
        if (lane < KNN) {
            int iq = ib + r;
            size_t o1 = (size_t)(b * KNN + lane) * NPTS + iq;
            out[o1] = (float)(u32)(myk & (u64)(NPTS - 1));
            out[(size_t)NB * KNN * NPTS + o1] = ord2f((u32)(myk >> 13));
        }
    }
}

extern "C" void kernel_launch(void* const* d_in, const int* in_sizes, int n_in,
                              void* d_out, int out_size, void* d_ws, size_t ws_size,
                              hipStream_t stream) {
    const float* pos = (const float*)d_in[0];
    float* out = (float*)d_out;
    float4* pos8 = (float4*)d_ws;   // 4*4096*2*16 B = 512 KB scratch

    pack_kernel<<<dim3(NB * NPAIR / 256), dim3(256), 0, stream>>>(pos, pos8);
    knn_kernel<<<dim3(NB * NPTS / 8), dim3(256), 0, stream>>>(pos8, out);
}